// Round 2
// baseline (3360.666 us; speedup 1.0000x reference)
//
#include <hip/hip_runtime.h>

// Problem constants (setup_inputs fixed: x=(2,256,512,512) fp32, H=W=512)
#define BB 2
#define CC 256
#define HH 512
#define WW 512
#define PS 52               // patch size
#define NW 9                // patches per row/col
#define NP 81               // patches total
#define COV 468             // covered extent = 9*52
#define PLANE (HH*WW)       // 262144
#define CHW (CC*PLANE)
#define SP (PS*PS)          // 2704

// workspace layout (floats):
//   S[2][81][256] = 41472 | pn[2][81] = 162 | gsum[512] | cosv[162] | sel (4 ints)
#define WS_S     0
#define WS_PN    41472
#define WS_GSUM  41634
#define WS_ZTOT  42146      // floats to zero (S, pn, gsum)
#define WS_COS   42146
#define WS_SEL   42308

// ---------------- K0: zero the accumulated workspace ----------------
__global__ __launch_bounds__(256) void zero_kernel(float* __restrict__ ws) {
    int i = blockIdx.x * 256 + threadIdx.x;
    if (i < WS_ZTOT) ws[i] = 0.f;
}

// ---------------- K1: fused gather/stats/apply(identity)/GAP/border, LDS-free ----------------
// Block = (cg in 0..15, h in 0..511, b). 256 threads; lane owns (c2 = t>>4, wq = t&15).
// Each lane gathers its own mask values mask[w][c] = x[du = w'*256+c] directly from
// global (no LDS tile, no barrier), multiplies by x at the out position, stores
// full-line float4, and accumulates S-bin / pn / gap contributions in registers.
__global__ __launch_bounds__(256) void mega_kernel(const float* __restrict__ x,
                                                   float* __restrict__ out,
                                                   float* __restrict__ S,
                                                   float* __restrict__ pn,
                                                   float* __restrict__ gsum) {
    const int cg = blockIdx.x;        // 0..15  (16-channel group)
    const int h  = blockIdx.y;        // 0..511
    const int b  = blockIdx.z;        // 0..1
    const int t  = threadIdx.x;       // 0..255
    const int c2 = t >> 4;            // 0..15  channel within group
    const int wq = t & 15;            // float4 column phase
    const int ch = cg * 16 + c2;      // absolute channel / c' bin
    const float* xb = x + (size_t)b * CHW;
    float* ob = out + (size_t)b * CHW;

    const size_t rowoff = (size_t)ch * PLANE + (size_t)h * WW;
    const float4* xrow = (const float4*)(xb + rowoff);
    float4* orow = (float4*)(ob + rowoff);

    float gacc = 0.f;

    if (h >= COV) {
        // pure border row: out = 0, accumulate GAP only
        #pragma unroll
        for (int i = 0; i < 8; i++) {
            int w4 = wq + 16 * i;
            float4 v = xrow[w4];
            gacc += v.x + v.y + v.z + v.w;
            orow[w4] = make_float4(0.f, 0.f, 0.f, 0.f);
        }
        #pragma unroll
        for (int o = 8; o > 0; o >>= 1) gacc += __shfl_down(gacc, o, 16);
        if (wq == 0) atomicAdd(gsum + b * CC + ch, gacc);
        return;
    }

    const int ph = h / PS;
    const int sh = h - ph * PS;
    const int s0 = sh * PS;
    const float* prow = xb + (size_t)(ph * PS) * WW;   // top-left row of patch-row ph

    // per-lane stats: this lane only ever touches bin c' = ch, patches (ph, pw 0..8)
    float sacc[NW];
    #pragma unroll
    for (int p = 0; p < NW; p++) sacc[p] = 0.f;
    float qacc = 0.f;

    #pragma unroll
    for (int i = 0; i < 8; i++) {
        int w4 = wq + 16 * i;         // 0..127 ; cols [4*w4, 4*w4+4)
        float4 v = xrow[w4];
        gacc += v.x + v.y + v.z + v.w;
        float4 ov;
        if (w4 < 117) {               // 117*4 = 468 covered cols
            float m[4];
            #pragma unroll
            for (int j = 0; j < 4; j++) {
                int w = w4 * 4 + j;           // global col 0..467
                int pw = w / PS;              // patch col
                int sw = w - pw * PS;         // col inside patch
                unsigned du  = (unsigned)(s0 + sw) * 256u + (unsigned)ch;
                unsigned chs = du / (unsigned)SP;
                unsigned rem = du - chs * (unsigned)SP;
                unsigned kh  = rem / (unsigned)PS;
                unsigned kw  = rem - kh * (unsigned)PS;
                float g = prow[(size_t)chs * PLANE + pw * PS + kh * WW + kw];
                m[j] = g;
                sacc[pw] += g;
                qacc += g * g;
            }
            ov.x = m[0] * v.x;
            ov.y = m[1] * v.y;
            ov.z = m[2] * v.z;
            ov.w = m[3] * v.w;
        } else {
            ov = make_float4(0.f, 0.f, 0.f, 0.f);
        }
        orow[w4] = ov;
    }

    // ---- reduce stats across the 16 wq lanes of this channel (width-16 shuffle) ----
    #pragma unroll
    for (int o = 8; o > 0; o >>= 1) {
        gacc += __shfl_down(gacc, o, 16);
        qacc += __shfl_down(qacc, o, 16);
        #pragma unroll
        for (int p = 0; p < NW; p++) sacc[p] += __shfl_down(sacc[p], o, 16);
    }
    if (wq == 0) {
        atomicAdd(gsum + b * CC + ch, gacc);
        #pragma unroll
        for (int p = 0; p < NW; p++)
            atomicAdd(S + ((size_t)(b * NP + ph * NW + p)) * 256 + ch, sacc[p]);
    } else if (wq == 1) {
        // qacc fully reduced only at wq==0; recompute via bcast from lane wq==0 of this c2
    }
    // pn: qacc at wq==0 holds the 16-lane sum for (this h, this ch, all 9 pw merged).
    // pn is a sum over ALL du of the patch -> channel-major bins irrelevant; just add.
    if (wq == 0) {
        // qacc currently sums squares over this lane-group's 468 covered cols of row h,
        // i.e. over all 9 patches in patch-row ph. pn needs per-patch sums: recompute
        // from sacc? No: squares can't be split post-hoc. Accumulate per-patch instead:
    }
    (void)0;
}

// NOTE: per-patch qacc handled below in a corrected second version of the stats path.
// (See mega_kernel2 — the actual kernel used.)

// Corrected mega kernel: per-patch sum-of-squares kept in registers (9 accumulators).
__global__ __launch_bounds__(256) void mega_kernel2(const float* __restrict__ x,
                                                    float* __restrict__ out,
                                                    float* __restrict__ S,
                                                    float* __restrict__ pn,
                                                    float* __restrict__ gsum) {
    const int cg = blockIdx.x;        // 0..15
    const int h  = blockIdx.y;        // 0..511
    const int b  = blockIdx.z;        // 0..1
    const int t  = threadIdx.x;       // 0..255
    const int c2 = t >> 4;
    const int wq = t & 15;
    const int ch = cg * 16 + c2;
    const float* xb = x + (size_t)b * CHW;
    float* ob = out + (size_t)b * CHW;

    const size_t rowoff = (size_t)ch * PLANE + (size_t)h * WW;
    const float4* xrow = (const float4*)(xb + rowoff);
    float4* orow = (float4*)(ob + rowoff);

    float gacc = 0.f;

    if (h >= COV) {
        #pragma unroll
        for (int i = 0; i < 8; i++) {
            int w4 = wq + 16 * i;
            float4 v = xrow[w4];
            gacc += v.x + v.y + v.z + v.w;
            orow[w4] = make_float4(0.f, 0.f, 0.f, 0.f);
        }
        #pragma unroll
        for (int o = 8; o > 0; o >>= 1) gacc += __shfl_down(gacc, o, 16);
        if (wq == 0) atomicAdd(gsum + b * CC + ch, gacc);
        return;
    }

    const int ph = h / PS;
    const int sh = h - ph * PS;
    const int s0 = sh * PS;
    const float* prow = xb + (size_t)(ph * PS) * WW;

    float sacc[NW], qpat[NW];
    #pragma unroll
    for (int p = 0; p < NW; p++) { sacc[p] = 0.f; qpat[p] = 0.f; }

    #pragma unroll
    for (int i = 0; i < 8; i++) {
        int w4 = wq + 16 * i;
        float4 v = xrow[w4];
        gacc += v.x + v.y + v.z + v.w;
        float4 ov;
        if (w4 < 117) {
            // cols [4*w4, 4*w4+4): within one patch except when crossing k*52
            float m[4];
            #pragma unroll
            for (int j = 0; j < 4; j++) {
                int w = w4 * 4 + j;
                int pw = w / PS;
                int sw = w - pw * PS;
                unsigned du  = (unsigned)(s0 + sw) * 256u + (unsigned)ch;
                unsigned chs = du / (unsigned)SP;
                unsigned rem = du - chs * (unsigned)SP;
                unsigned kh  = rem / (unsigned)PS;
                unsigned kw  = rem - kh * (unsigned)PS;
                float g = prow[(size_t)chs * PLANE + pw * PS + kh * WW + kw];
                m[j] = g;
                sacc[pw] += g;
                qpat[pw] += g * g;
            }
            ov.x = m[0] * v.x;
            ov.y = m[1] * v.y;
            ov.z = m[2] * v.z;
            ov.w = m[3] * v.w;
        } else {
            ov = make_float4(0.f, 0.f, 0.f, 0.f);
        }
        orow[w4] = ov;
    }

    // reduce across the 16 wq lanes (width-16 shuffle; lanes of one channel are contiguous)
    #pragma unroll
    for (int o = 8; o > 0; o >>= 1) {
        gacc += __shfl_down(gacc, o, 16);
        #pragma unroll
        for (int p = 0; p < NW; p++) {
            sacc[p] += __shfl_down(sacc[p], o, 16);
            qpat[p] += __shfl_down(qpat[p], o, 16);
        }
    }
    if (wq == 0) {
        atomicAdd(gsum + b * CC + ch, gacc);
        size_t Sbase = ((size_t)(b * NP + ph * NW)) * 256 + ch;
        #pragma unroll
        for (int p = 0; p < NW; p++) {
            atomicAdd(S + Sbase + (size_t)p * 256, sacc[p]);
            atomicAdd(pn + b * NP + ph * NW + p, qpat[p]);
        }
    }
}

// ---------------- K2: cosine per (b, l) ----------------
__global__ __launch_bounds__(256) void cos_kernel(const float* __restrict__ gsum,
                                                  const float* __restrict__ S,
                                                  const float* __restrict__ pn,
                                                  float* __restrict__ cosv) {
    int l = blockIdx.x;   // 0..80
    int b = blockIdx.y;
    int t = threadIdx.x;  // 0..255 == c'
    float g = gsum[b * CC + t] * (1.0f / PLANE);
    float d  = S[((size_t)(b * NP + l)) * 256 + t] * g;
    float gg = g * g;
    #pragma unroll
    for (int o = 32; o > 0; o >>= 1) { d += __shfl_down(d, o); gg += __shfl_down(gg, o); }
    __shared__ float rd[4], rg[4];
    int wv = t >> 6;
    if ((t & 63) == 0) { rd[wv] = d; rg[wv] = gg; }
    __syncthreads();
    if (t == 0) {
        float dt = rd[0] + rd[1] + rd[2] + rd[3];
        float gt = rg[0] + rg[1] + rg[2] + rg[3];
        float gnorm = sqrtf(gt) * (float)PS;
        float pnorm = sqrtf(pn[b * NP + l]);
        cosv[b * NP + l] = dt / fmaxf(gnorm * pnorm, 1e-8f);
    }
}

// ---------------- K3: argmax/argmin scan (first-index ties, matches jnp) ----------------
__global__ void sel_kernel(const float* __restrict__ cosv, int* __restrict__ sel) {
    int b = threadIdx.x;
    if (b < BB) {
        float best = -1e30f, worst = 1e30f;
        int bi = 0, wi = 0;
        for (int l = 0; l < NP; l++) {
            float c = cosv[b * NP + l];
            if (c > best)  { best  = c; bi = l; }
            if (c < worst) { worst = c; wi = l; }
        }
        sel[b * 2 + 0] = bi;
        sel[b * 2 + 1] = wi;
    }
}

// ---------------- K4: fixup patch idx <- gather from patch ids ----------------
__global__ __launch_bounds__(256) void fixup_kernel(const float* __restrict__ x,
                                                    float* __restrict__ out,
                                                    const int* __restrict__ sel) {
    int tile_i = blockIdx.x;        // 0..171 = tc(4) * ts(43)
    int tc = tile_i / 43;
    int ts = tile_i - tc * 43;
    int b = blockIdx.y;
    int l = sel[b * 2 + 0];         // idx (dest patch)
    int srcp = sel[b * 2 + 1];      // ids (source patch)
    int ph = l / NW, pw = l - ph * NW;
    int sph = srcp / NW, spw = srcp - sph * NW;

    const float* xb = x + (size_t)b * CHW;
    const float* src_base = xb + (size_t)(sph * PS) * WW + (spw * PS);

    __shared__ float tb[64][65];
    int cb = tc * 64;
    int sb = ts * 64;
    int t = threadIdx.x;

    {   // load: lanes sweep c' (consecutive du -> coalesced-ish)
        int cl = t & 63;
        int sr = t >> 6;
        #pragma unroll
        for (int i = 0; i < 16; i++) {
            int s_l = i * 4 + sr;
            int s_g = sb + s_l;
            float v = 0.f;
            if (s_g < SP) {
                unsigned du  = (unsigned)s_g * 256u + (unsigned)(cb + cl);
                unsigned chs = du / (unsigned)SP;
                unsigned rem = du - chs * (unsigned)SP;
                unsigned kh  = rem / (unsigned)PS;
                unsigned kw  = rem - kh * (unsigned)PS;
                v = src_base[(size_t)chs * PLANE + kh * WW + kw];
            }
            tb[s_l][cl] = v;
        }
    }
    __syncthreads();
    {   // store: lanes sweep s (contiguous w runs); multiply by x at out position
        int sl = t & 63;
        int cr = t >> 6;
        int s_g = sb + sl;
        if (s_g < SP) {
            unsigned shh = (unsigned)s_g / PS;
            unsigned sww = (unsigned)s_g - shh * PS;
            size_t pos = (size_t)(ph * PS + shh) * WW + (pw * PS + sww);
            #pragma unroll
            for (int i = 0; i < 16; i++) {
                int c_l = i * 4 + cr;
                size_t off = (size_t)(cb + c_l) * PLANE + pos;
                out[(size_t)b * CHW + off] = tb[sl][c_l] * xb[off];
            }
        }
    }
}

extern "C" void kernel_launch(void* const* d_in, const int* in_sizes, int n_in,
                              void* d_out, int out_size, void* d_ws, size_t ws_size,
                              hipStream_t stream) {
    const float* x = (const float*)d_in[0];
    float* out = (float*)d_out;
    float* ws = (float*)d_ws;

    float* S    = ws + WS_S;
    float* pn   = ws + WS_PN;
    float* gsum = ws + WS_GSUM;
    float* cosv = ws + WS_COS;
    int*   sel  = (int*)(ws + WS_SEL);

    zero_kernel<<<dim3((WS_ZTOT + 255) / 256), dim3(256), 0, stream>>>(ws);
    mega_kernel2<<<dim3(16, HH, BB), dim3(256), 0, stream>>>(x, out, S, pn, gsum);
    cos_kernel<<<dim3(NP, BB), dim3(256), 0, stream>>>(gsum, S, pn, cosv);
    sel_kernel<<<dim3(1), dim3(64), 0, stream>>>(cosv, sel);
    fixup_kernel<<<dim3(172, BB), dim3(256), 0, stream>>>(x, out, sel);
}